// Round 4
// baseline (391.295 us; speedup 1.0000x reference)
//
#include <hip/hip_runtime.h>

#define BB 2
#define NTOK 4096
#define DIM 128
#define INNER 256
#define HEADS 4
#define DH 64
#define QS 0.18033688011112043f  // 0.125 * log2(e)

typedef unsigned short u16;
typedef __attribute__((ext_vector_type(8))) short bf16x8;
typedef __attribute__((ext_vector_type(16))) float f32x16;

__device__ inline unsigned f2bf1(float f) {
  union { float f; unsigned u; } a; a.f = f;
  return (a.u + 0x7fffu + ((a.u >> 16) & 1u)) >> 16;  // RNE
}
__device__ inline float bf2f(u16 h) {
  union { unsigned u; float f; } a; a.u = ((unsigned)h) << 16;
  return a.f;
}
__device__ inline unsigned cvtpk(float lo, float hi) {
  unsigned r;
  asm("v_cvt_pk_bf16_f32 %0, %1, %2" : "=v"(r) : "v"(lo), "v"(hi));
  return r;
}

// ---------------------------------------------------------------- kernel 1
// x + pos-enc, depthwise 3x3 (SAME); writes bf16 n-major [b][n][128]
__global__ __launch_bounds__(256) void k_pe_dw(const float* __restrict__ x,
    const float* __restrict__ pew, const float* __restrict__ peb,
    const float* __restrict__ dw, u16* __restrict__ out) {
  int bc = blockIdx.x;              // b*128 + c
  int b = bc >> 7, c = bc & 127;
  float s0 = pew[c * 2 + 0] * (1.0f / 63.0f);
  float s1 = pew[c * 2 + 1] * (1.0f / 63.0f);
  float pb = peb[c];
  float w[9];
#pragma unroll
  for (int q = 0; q < 9; ++q) w[q] = dw[c * 9 + q];
  const float* xb = x + (size_t)bc * NTOK;
  u16* ob = out + (size_t)b * NTOK * DIM + c;
  for (int p = threadIdx.x; p < NTOK; p += 256) {
    int i = p >> 6, j = p & 63;
    float acc = 0.f;
#pragma unroll
    for (int di = 0; di < 3; ++di) {
      int ii = i + di - 1;
      if ((unsigned)ii < 64u) {
#pragma unroll
        for (int dj = 0; dj < 3; ++dj) {
          int jj = j + dj - 1;
          if ((unsigned)jj < 64u) {
            float xv = xb[ii * 64 + jj] + ii * s0 + jj * s1 + pb;
            acc += xv * w[di * 3 + dj];
          }
        }
      }
    }
    ob[(size_t)p * DIM] = (u16)f2bf1(acc);
  }
}

// ---------------------------------------------------------------- kernel 5
// depthwise 3x3 on att fp32 [b][256][n]; writes bf16 n-major [b][n][256]
__global__ __launch_bounds__(256) void k_dw(const float* __restrict__ x,
    const float* __restrict__ dw, u16* __restrict__ out) {
  int bc = blockIdx.x;
  int b = bc >> 8, c = bc & 255;
  float w[9];
#pragma unroll
  for (int q = 0; q < 9; ++q) w[q] = dw[c * 9 + q];
  const float* xb = x + (size_t)bc * NTOK;
  u16* ob = out + (size_t)b * NTOK * INNER + c;
  for (int p = threadIdx.x; p < NTOK; p += 256) {
    int i = p >> 6, j = p & 63;
    float acc = 0.f;
#pragma unroll
    for (int di = 0; di < 3; ++di) {
      int ii = i + di - 1;
      if ((unsigned)ii < 64u) {
#pragma unroll
        for (int dj = 0; dj < 3; ++dj) {
          int jj = j + dj - 1;
          if ((unsigned)jj < 64u) acc += xb[ii * 64 + jj] * w[di * 3 + dj];
        }
      }
    }
    ob[(size_t)p * INNER] = (u16)f2bf1(acc);
  }
}

// ---------------------------------------------------------------- kernels 2/6
// MFMA bf16 GEMM: C[M, 4096] = W[M,K](fp32) @ Yb^T, Yb = [b][4096][K] bf16.
// 128 x NTILE tile, 4 waves, 32x32x16 MFMA, BK=64, XOR-swizzled LDS.
template <int K, int EPI, int NTILE>
__global__ __launch_bounds__(256) void k_gemm_bf(
    const float* __restrict__ W, const u16* __restrict__ Yb,
    float* __restrict__ q_o, float* __restrict__ k_o,
    u16* __restrict__ v_t, int Mtiles) {
  constexpr int FN = NTILE >> 6;            // 2 for 128, 1 for 64
  constexpr int NT_CNT = NTOK / NTILE;
  __shared__ u16 Wl[128 * 64];
  __shared__ u16 Yl[NTILE * 64];
  int gid = blockIdx.x;
  int nt = gid % NT_CNT;
  int mt = (gid / NT_CNT) % Mtiles;
  int b = gid / (NT_CNT * Mtiles);
  int t = threadIdx.x;
  int w = t >> 6, l = t & 63;
  int wm = w >> 1, wn = w & 1;
  int hi = l >> 5, lq = l & 31;

  f32x16 acc[2][FN];
#pragma unroll
  for (int fm = 0; fm < 2; ++fm)
#pragma unroll
    for (int fn = 0; fn < FN; ++fn)
#pragma unroll
      for (int r = 0; r < 16; ++r) acc[fm][fn][r] = 0.f;

  const float* Wbase = W + (size_t)(mt * 128) * K;
  const u16* Ybase = Yb + ((size_t)(b * NTOK) + nt * NTILE) * K;

  for (int k0 = 0; k0 < K; k0 += 64) {
#pragma unroll
    for (int u = 0; u < 4; ++u) {           // W: 1024 granules of 8 bf16
      int gI = t + 256 * u;
      int row = gI >> 3, g = gI & 7;
      float4 f0 = *(const float4*)(Wbase + (size_t)row * K + k0 + g * 8);
      float4 f1 = *(const float4*)(Wbase + (size_t)row * K + k0 + g * 8 + 4);
      uint4 uu;
      uu.x = cvtpk(f0.x, f0.y); uu.y = cvtpk(f0.z, f0.w);
      uu.z = cvtpk(f1.x, f1.y); uu.w = cvtpk(f1.z, f1.w);
      *(uint4*)&Wl[row * 64 + 8 * (g ^ (row & 7))] = uu;
    }
#pragma unroll
    for (int u = 0; u < NTILE / 32; ++u) {  // Y: NTILE*8 granules
      int gI = t + 256 * u;
      int row = gI >> 3, g = gI & 7;
      uint4 yv = *(const uint4*)(Ybase + (size_t)row * K + k0 + g * 8);
      *(uint4*)&Yl[row * 64 + 8 * (g ^ (row & 7))] = yv;
    }
    __syncthreads();
#pragma unroll
    for (int ks = 0; ks < 4; ++ks) {
      bf16x8 aF[2], bF[FN];
#pragma unroll
      for (int fm = 0; fm < 2; ++fm) {
        int row = wm * 64 + fm * 32 + lq;
        aF[fm] = *(bf16x8*)&Wl[row * 64 + 8 * ((2 * ks + hi) ^ (row & 7))];
      }
#pragma unroll
      for (int fn = 0; fn < FN; ++fn) {
        int row = wn * 32 * FN + fn * 32 + lq;
        bF[fn] = *(bf16x8*)&Yl[row * 64 + 8 * ((2 * ks + hi) ^ (row & 7))];
      }
#pragma unroll
      for (int fm = 0; fm < 2; ++fm)
#pragma unroll
        for (int fn = 0; fn < FN; ++fn)
          acc[fm][fn] = __builtin_amdgcn_mfma_f32_32x32x16_bf16(
              aF[fm], bF[fn], acc[fm][fn], 0, 0, 0);
    }
    __syncthreads();
  }

#pragma unroll
  for (int fm = 0; fm < 2; ++fm)
#pragma unroll
    for (int fn = 0; fn < FN; ++fn)
#pragma unroll
      for (int reg = 0; reg < 16; ++reg) {
        int rl = (reg & 3) + 8 * (reg >> 2) + 4 * hi;
        int o = mt * 128 + wm * 64 + fm * 32 + rl;
        int n = nt * NTILE + wn * 32 * FN + fn * 32 + lq;
        float val = acc[fm][fn][reg];
        if (EPI == 0) {
          int part = o >> 8, rr = o & 255;
          int head = rr & 3, d = rr >> 2;
          if (part == 0)
            q_o[((size_t)(b * HEADS + head) * NTOK + n) * DH + d] = val;
          else if (part == 1)
            k_o[((size_t)(b * HEADS + head) * NTOK + n) * DH + d] = val;
          else
            v_t[((size_t)(b * HEADS + head) * DH + d) * NTOK + n] =
                (u16)f2bf1(val);
        } else {
          q_o[((size_t)(b * DIM) + o) * NTOK + n] = val;
        }
      }
}

// ---------------------------------------------------------------- kernel 3
// per-head LN over d for q,k; bf16 in place. Grid-stride over 65536 rows.
__global__ __launch_bounds__(256) void k_lnqk(float* __restrict__ qh,
    float* __restrict__ kh, const float* __restrict__ nqw,
    const float* __restrict__ nqb, const float* __restrict__ nkw,
    const float* __restrict__ nkb) {
  int lane = threadIdx.x & 63;
  for (int row = blockIdx.x * 4 + (threadIdx.x >> 6); row < 65536;
       row += 2048 * 4) {
    int buf = row >> 15;           // 0 = q, 1 = k
    int r = row & 32767;           // bh*4096 + n
    int head = (r >> 12) & 3;
    float* base = (buf ? kh : qh) + (size_t)r * DH;
    const float* wp = (buf ? nkw : nqw) + head * DH;
    const float* bp = (buf ? nkb : nqb) + head * DH;
    float v = base[lane];
    float s1 = v, s2 = v * v;
#pragma unroll
    for (int off = 1; off < 64; off <<= 1) {
      s1 += __shfl_xor(s1, off);
      s2 += __shfl_xor(s2, off);
    }
    float mu = s1 * (1.f / 64.f);
    float var = s2 * (1.f / 64.f) - mu * mu;
    float y = (v - mu) * rsqrtf(var + 1e-6f) * wp[lane] + bp[lane];
    if (buf == 0) y *= QS;
    u16* bb = (u16*)base;          // row-local in-place: safe
    bb[lane] = (u16)f2bf1(y);
  }
}

// ---------------------------------------------------------------- kernel 4
// MFMA flash attention. Block = (bh, 64-q tile); 8 waves = 2 qg x 4 kv-
// quarters (1024 kv each, 16 tiles of 64). K/V^T bf16 in LDS per quarter,
// XOR swizzle; T14 async-stage; T13 defer-max; exp2 domain. 4-way LDS merge.
// Epilogue: O/l + v skip (bf16 V^T), head-LN, scatter [b][d*4+head][n].
__global__ __launch_bounds__(512, 2) void k_attn3(
    const u16* __restrict__ qb, const u16* __restrict__ kb,
    const u16* __restrict__ vtb, const float* __restrict__ now,
    const float* __restrict__ nob, float* __restrict__ att) {
  __shared__ __align__(16) u16 kvbuf[32768];  // 64KB: [h][K 4096 | V 4096]
  __shared__ float nw[DH], nb[DH];
  const int bh = blockIdx.x >> 6, qt = blockIdx.x & 63;
  const int b = bh >> 2, head = bh & 3;
  const int t = threadIdx.x;
  const int w = t >> 6, l = t & 63;
  const int qg = w & 1, h = w >> 1;
  const int hi = l >> 5, lq = l & 31;
  if (t < DH) { nw[t] = now[head * DH + t]; nb[t] = nob[head * DH + t]; }

  const int q0 = qt * 64 + qg * 32;
  const u16* qrow = qb + (size_t)(bh * NTOK + q0 + lq) * 128;  // 128-u16 rows
  bf16x8 qf[4];
#pragma unroll
  for (int ks = 0; ks < 4; ++ks)
    qf[ks] = *(const bf16x8*)(qrow + 16 * ks + 8 * hi);

  // staging: 128 threads per quarter h
  const int st = t & 127;
  const u16* kbase = kb + (size_t)(bh * NTOK) * 128;
  const u16* vbase = vtb + (size_t)(bh * DH) * NTOK;
  uint4 kr[4], vr[4];
  auto loadTile = [&](int s) {
    int kv0 = h * 1024 + s * 64;
#pragma unroll
    for (int u = 0; u < 4; ++u) {
      int gI = st + 128 * u;
      int row = gI >> 3, g = gI & 7;
      kr[u] = *(const uint4*)(kbase + (size_t)(kv0 + row) * 128 + g * 8);
      vr[u] = *(const uint4*)(vbase + (size_t)row * NTOK + kv0 + g * 8);
    }
  };
  loadTile(0);

  f32x16 oT0, oT1;
#pragma unroll
  for (int i = 0; i < 16; ++i) { oT0[i] = 0.f; oT1[i] = 0.f; }
  float m_s = -1e30f, l_s = 0.f;
  const u16* KL = kvbuf + h * 8192;
  const u16* VL = KL + 4096;

  for (int s = 0; s < 16; ++s) {
    __syncthreads();  // readers done with tile s-1
#pragma unroll
    for (int u = 0; u < 4; ++u) {
      int gI = st + 128 * u;
      int row = gI >> 3, g = gI & 7;
      *(uint4*)&kvbuf[h * 8192 + row * 64 + 8 * (g ^ (row & 7))] = kr[u];
      *(uint4*)&kvbuf[h * 8192 + 4096 + row * 64 + 8 * (g ^ (row & 7))] = vr[u];
    }
    __syncthreads();  // tile s visible
    if (s < 15) loadTile(s + 1);  // in flight under compute

    // ---- S^T = K . Q^T
    f32x16 sT0, sT1;
#pragma unroll
    for (int i = 0; i < 16; ++i) { sT0[i] = 0.f; sT1[i] = 0.f; }
#pragma unroll
    for (int ks = 0; ks < 4; ++ks) {
      bf16x8 a0 = *(bf16x8*)&KL[lq * 64 + 8 * ((2 * ks + hi) ^ (lq & 7))];
      bf16x8 a1 = *(bf16x8*)&KL[(32 + lq) * 64 + 8 * ((2 * ks + hi) ^ (lq & 7))];
      sT0 = __builtin_amdgcn_mfma_f32_32x32x16_bf16(a0, qf[ks], sT0, 0, 0, 0);
      sT1 = __builtin_amdgcn_mfma_f32_32x32x16_bf16(a1, qf[ks], sT1, 0, 0, 0);
    }
    // ---- online softmax (exp2 domain) + T13 defer-max
    float mo = fmaxf(sT0[0], sT1[0]);
#pragma unroll
    for (int i = 1; i < 16; ++i) mo = fmaxf(mo, fmaxf(sT0[i], sT1[i]));
    mo = fmaxf(mo, __shfl_xor(mo, 32));
    float mn = fmaxf(m_s, mo);
    if (!__all(mn - m_s <= 8.0f)) {
      float alpha = exp2f(m_s - mn);
      m_s = mn;
      l_s *= alpha;
#pragma unroll
      for (int i = 0; i < 16; ++i) { oT0[i] *= alpha; oT1[i] *= alpha; }
    }
    unsigned pw0[8], pw1[8];
    float rs = 0.f;
#pragma unroll
    for (int i = 0; i < 8; ++i) {
      float e0 = exp2f(sT0[2 * i] - m_s);
      float e1 = exp2f(sT0[2 * i + 1] - m_s);
      rs += e0 + e1;
      pw0[i] = cvtpk(e0, e1);
      float f0 = exp2f(sT1[2 * i] - m_s);
      float f1 = exp2f(sT1[2 * i + 1] - m_s);
      rs += f0 + f1;
      pw1[i] = cvtpk(f0, f1);
    }
    rs += __shfl_xor(rs, 32);
    l_s += rs;
    // ---- P^T B-frags in-register
    bf16x8 pf[4];
#pragma unroll
    for (int ks = 0; ks < 4; ++ks) {
      unsigned e0, e1, e2, e3;
      if (ks == 0)      { e0 = pw0[0]; e1 = pw0[1]; e2 = pw0[2]; e3 = pw0[3]; }
      else if (ks == 1) { e0 = pw0[4]; e1 = pw0[5]; e2 = pw0[6]; e3 = pw0[7]; }
      else if (ks == 2) { e0 = pw1[0]; e1 = pw1[1]; e2 = pw1[2]; e3 = pw1[3]; }
      else              { e0 = pw1[4]; e1 = pw1[5]; e2 = pw1[6]; e3 = pw1[7]; }
      unsigned z0 = hi ? e0 : e2;
      unsigned z1 = hi ? e1 : e3;
      unsigned rr0 = (unsigned)__shfl_xor((int)z0, 32);
      unsigned rr1 = (unsigned)__shfl_xor((int)z1, 32);
      union { unsigned u[4]; bf16x8 v; } U;
      if (hi) { U.u[0] = rr0; U.u[1] = rr1; U.u[2] = e2; U.u[3] = e3; }
      else    { U.u[0] = e0;  U.u[1] = e1;  U.u[2] = rr0; U.u[3] = rr1; }
      pf[ks] = U.v;
    }
    // ---- O^T += V^T . P^T
#pragma unroll
    for (int ks = 0; ks < 4; ++ks) {
      bf16x8 v0 = *(bf16x8*)&VL[lq * 64 + 8 * ((2 * ks + hi) ^ (lq & 7))];
      bf16x8 v1 = *(bf16x8*)&VL[(32 + lq) * 64 + 8 * ((2 * ks + hi) ^ (lq & 7))];
      oT0 = __builtin_amdgcn_mfma_f32_32x32x16_bf16(v0, pf[ks], oT0, 0, 0, 0);
      oT1 = __builtin_amdgcn_mfma_f32_32x32x16_bf16(v1, pf[ks], oT1, 0, 0, 0);
    }
  }

  // ---- 4-way merge via LDS (reuse kvbuf)
  __syncthreads();
  float* mrg = (float*)kvbuf;            // 6 x 2048 f32 O-partials
  float* mstore = mrg + 12288;           // [3][128]
  float* lstore = mstore + 384;
  if (h > 0) {
    float* mg = mrg + ((h - 1) * 2 + qg) * 2048;
#pragma unroll
    for (int i = 0; i < 16; ++i) {
      mg[i * 64 + l] = oT0[i];
      mg[(16 + i) * 64 + l] = oT1[i];
    }
    mstore[(h - 1) * 128 + qg * 64 + l] = m_s;
    lstore[(h - 1) * 128 + qg * 64 + l] = l_s;
  }
  __syncthreads();
  if (h == 0) {
    float ov[32];
#pragma unroll
    for (int i = 0; i < 16; ++i) { ov[i] = oT0[i]; ov[16 + i] = oT1[i]; }
#pragma unroll
    for (int hp = 1; hp < 4; ++hp) {
      float m1 = mstore[(hp - 1) * 128 + qg * 64 + l];
      float l1 = lstore[(hp - 1) * 128 + qg * 64 + l];
      const float* mg = mrg + ((hp - 1) * 2 + qg) * 2048;
      float M = fmaxf(m_s, m1);
      float a0 = exp2f(m_s - M), a1 = exp2f(m1 - M);
#pragma unroll
      for (int i = 0; i < 32; ++i) ov[i] = ov[i] * a0 + mg[i * 64 + l] * a1;
      l_s = l_s * a0 + l1 * a1;
      m_s = M;
    }
    float inv = 1.f / l_s;
#pragma unroll
    for (int i = 0; i < 32; ++i) ov[i] *= inv;
    int n = q0 + lq;
    // skip: += v (bf16 V^T)
#pragma unroll
    for (int dt = 0; dt < 2; ++dt)
#pragma unroll
      for (int g = 0; g < 4; ++g)
#pragma unroll
        for (int r = 0; r < 4; ++r) {
          int d = dt * 32 + g * 8 + hi * 4 + r;
          ov[dt * 16 + g * 4 + r] +=
              bf2f(vtb[((size_t)(bh * DH) + d) * NTOK + n]);
        }
    float s1 = 0.f, s2 = 0.f;
#pragma unroll
    for (int i = 0; i < 32; ++i) { s1 += ov[i]; s2 += ov[i] * ov[i]; }
    s1 += __shfl_xor(s1, 32);
    s2 += __shfl_xor(s2, 32);
    float mu = s1 * (1.f / 64.f);
    float va = s2 * (1.f / 64.f) - mu * mu;
    float ri = rsqrtf(va + 1e-6f);
    float* ob = att + (size_t)b * INNER * NTOK + n;
#pragma unroll
    for (int dt = 0; dt < 2; ++dt)
#pragma unroll
      for (int g = 0; g < 4; ++g)
#pragma unroll
        for (int r = 0; r < 4; ++r) {
          int d = dt * 32 + g * 8 + hi * 4 + r;
          float y = (ov[dt * 16 + g * 4 + r] - mu) * ri * nw[d] + nb[d];
          ob[(size_t)(d * 4 + head) * NTOK] = y;
        }
  }
}

// ---------------------------------------------------------------- kernel 7
__global__ __launch_bounds__(256) void k_ln2d(const float* __restrict__ pw,
    const float* __restrict__ lnw, const float* __restrict__ lnb,
    float* __restrict__ out) {
  __shared__ float sh1[4][64], sh2[4][64];
  int b = blockIdx.x >> 6, nt = blockIdx.x & 63;
  int ln = threadIdx.x & 63, part = threadIdx.x >> 6;
  int n = nt * 64 + ln;
  const float* base = pw + (size_t)b * DIM * NTOK + n;
  float a1 = 0.f, a2 = 0.f;
  for (int c = part * 32; c < part * 32 + 32; ++c) {
    float v = base[(size_t)c * NTOK];
    a1 += v;
    a2 += v * v;
  }
  sh1[part][ln] = a1;
  sh2[part][ln] = a2;
  __syncthreads();
  float s1 = sh1[0][ln] + sh1[1][ln] + sh1[2][ln] + sh1[3][ln];
  float s2 = sh2[0][ln] + sh2[1][ln] + sh2[2][ln] + sh2[3][ln];
  float mu = s1 * (1.f / 128.f);
  float var = s2 * (1.f / 128.f) - mu * mu;
  float ri = rsqrtf(var + 1e-6f);
  float* ob = out + (size_t)b * DIM * NTOK + n;
  for (int c = part * 32; c < part * 32 + 32; ++c) {
    float v = base[(size_t)c * NTOK];
    ob[(size_t)c * NTOK] = (v - mu) * ri * lnw[c] + lnb[c];
  }
}

// ----------------------------------------------------------------
extern "C" void kernel_launch(void* const* d_in, const int* in_sizes, int n_in,
                              void* d_out, int out_size, void* d_ws,
                              size_t ws_size, hipStream_t stream) {
  const float* x      = (const float*)d_in[0];
  const float* pe_w   = (const float*)d_in[1];
  const float* pe_b   = (const float*)d_in[2];
  const float* qkv_dw = (const float*)d_in[3];
  const float* qkv_pw = (const float*)d_in[4];
  const float* out_dw = (const float*)d_in[5];
  const float* out_pw = (const float*)d_in[6];
  const float* nq_w   = (const float*)d_in[7];
  const float* nq_b   = (const float*)d_in[8];
  const float* nk_w   = (const float*)d_in[9];
  const float* nk_b   = (const float*)d_in[10];
  const float* no_w   = (const float*)d_in[11];
  const float* no_b   = (const float*)d_in[12];
  const float* ln_w   = (const float*)d_in[13];
  const float* ln_b   = (const float*)d_in[14];

  float* ws = (float*)d_ws;
  u16*   dwyb = (u16*)ws;                       // [2][4096][128] bf16 (2MB)
  float* qhb  = ws + (1u << 19);                // [8][4096][64] f32 -> bf16
  float* khb  = ws + (5u << 19);                // same
  u16*   vtb  = (u16*)(ws + (9u << 19));        // [8][64][4096] bf16 (4MB)
  float* att  = ws + (11u << 19);               // [2][256][4096] f32 (8MB)
  u16*   db16 = (u16*)khb;                      // reuse (k dead after attn)
  float* pwout = qhb;                           // reuse (q dead after attn)
  float* outp = (float*)d_out;

  k_pe_dw<<<dim3(BB * DIM), dim3(256), 0, stream>>>(x, pe_w, pe_b, qkv_dw, dwyb);
  k_gemm_bf<128, 0, 128><<<dim3(BB * 6 * 32), dim3(256), 0, stream>>>(
      qkv_pw, dwyb, qhb, khb, vtb, 6);
  k_lnqk<<<dim3(2048), dim3(256), 0, stream>>>(qhb, khb, nq_w, nq_b, nk_w, nk_b);
  k_attn3<<<dim3(512), dim3(512), 0, stream>>>(
      (const u16*)qhb, (const u16*)khb, vtb, no_w, no_b, att);
  k_dw<<<dim3(BB * INNER), dim3(256), 0, stream>>>(att, out_dw, db16);
  k_gemm_bf<256, 1, 64><<<dim3(BB * 1 * 64), dim3(256), 0, stream>>>(
      out_pw, db16, pwout, nullptr, nullptr, 1);
  k_ln2d<<<dim3(BB * 64), dim3(256), 0, stream>>>(pwout, ln_w, ln_b, outp);
}

// Round 5
// 296.504 us; speedup vs baseline: 1.3197x; 1.3197x over previous
//
#include <hip/hip_runtime.h>

#define BB 2
#define NTOK 4096
#define DIM 128
#define INNER 256
#define HEADS 4
#define DH 64
#define QS 0.18033688011112043f  // 0.125 * log2(e)

typedef unsigned short u16;
typedef __attribute__((ext_vector_type(8))) short bf16x8;
typedef __attribute__((ext_vector_type(16))) float f32x16;

__device__ inline unsigned f2bf1(float f) {
  union { float f; unsigned u; } a; a.f = f;
  return (a.u + 0x7fffu + ((a.u >> 16) & 1u)) >> 16;  // RNE
}
__device__ inline unsigned packbf(float lo, float hi) {
  return f2bf1(lo) | (f2bf1(hi) << 16);
}
__device__ inline float bf2f(u16 h) {
  union { unsigned u; float f; } a; a.u = ((unsigned)h) << 16;
  return a.f;
}
__device__ inline unsigned cvtpk(float lo, float hi) {
  unsigned r;
  asm("v_cvt_pk_bf16_f32 %0, %1, %2" : "=v"(r) : "v"(lo), "v"(hi));
  return r;
}

// ---------------------------------------------------------------- kernel 1
// x + pos-enc, depthwise 3x3; out bf16 [b][n][128], coalesced 64B chunks.
// grid = b(2) x cg(4) x ns(16) = 128 blocks; thread owns pixel n, 32 c.
__global__ __launch_bounds__(256) void k_pe_dw(const float* __restrict__ x,
    const float* __restrict__ pew, const float* __restrict__ peb,
    const float* __restrict__ dw, u16* __restrict__ out) {
  int bid = blockIdx.x;
  int ns = bid & 15, cg = (bid >> 4) & 3, b = bid >> 6;
  int p = ns * 256 + threadIdx.x;
  int i = p >> 6, j = p & 63;
  float res[32];
  const float* xc = x + ((size_t)(b * DIM + cg * 32)) * NTOK;
#pragma unroll 4
  for (int cl = 0; cl < 32; ++cl) {
    int c = cg * 32 + cl;
    float s0 = pew[c * 2] * (1.f / 63.f);
    float s1 = pew[c * 2 + 1] * (1.f / 63.f);
    float pb = peb[c];
    const float* xb = xc + (size_t)cl * NTOK;
    const float* wp = dw + c * 9;
    float acc = 0.f;
#pragma unroll
    for (int di = 0; di < 3; ++di) {
      int ii = i + di - 1;
      if ((unsigned)ii < 64u) {
#pragma unroll
        for (int dj = 0; dj < 3; ++dj) {
          int jj = j + dj - 1;
          if ((unsigned)jj < 64u) {
            float xv = xb[ii * 64 + jj] + ii * s0 + jj * s1 + pb;
            acc += xv * wp[di * 3 + dj];
          }
        }
      }
    }
    res[cl] = acc;
  }
  unsigned ow[16];
#pragma unroll
  for (int q = 0; q < 16; ++q) ow[q] = packbf(res[2 * q], res[2 * q + 1]);
  u16* ob = out + ((size_t)(b * NTOK) + p) * DIM + cg * 32;
#pragma unroll
  for (int q = 0; q < 4; ++q) *(uint4*)(ob + q * 8) = *(uint4*)&ow[q * 4];
}

// ---------------------------------------------------------------- kernel 5
// depthwise 3x3 on att f32 [b][256][n]; out bf16 [b][n][256] coalesced.
// grid = b(2) x cg(8) x ns(16) = 256 blocks.
__global__ __launch_bounds__(256) void k_dw(const float* __restrict__ x,
    const float* __restrict__ dw, u16* __restrict__ out) {
  int bid = blockIdx.x;
  int ns = bid & 15, cg = (bid >> 4) & 7, b = bid >> 7;
  int p = ns * 256 + threadIdx.x;
  int i = p >> 6, j = p & 63;
  float res[32];
  const float* xc = x + ((size_t)(b * INNER + cg * 32)) * NTOK;
#pragma unroll 4
  for (int cl = 0; cl < 32; ++cl) {
    int c = cg * 32 + cl;
    const float* xb = xc + (size_t)cl * NTOK;
    const float* wp = dw + c * 9;
    float acc = 0.f;
#pragma unroll
    for (int di = 0; di < 3; ++di) {
      int ii = i + di - 1;
      if ((unsigned)ii < 64u) {
#pragma unroll
        for (int dj = 0; dj < 3; ++dj) {
          int jj = j + dj - 1;
          if ((unsigned)jj < 64u) acc += xb[ii * 64 + jj] * wp[di * 3 + dj];
        }
      }
    }
    res[cl] = acc;
  }
  unsigned ow[16];
#pragma unroll
  for (int q = 0; q < 16; ++q) ow[q] = packbf(res[2 * q], res[2 * q + 1]);
  u16* ob = out + ((size_t)(b * NTOK) + p) * INNER + cg * 32;
#pragma unroll
  for (int q = 0; q < 4; ++q) *(uint4*)(ob + q * 8) = *(uint4*)&ow[q * 4];
}

// ---------------------------------------------------------------- kernels 2/6
// MFMA bf16 GEMM: C[M, 4096] = W[M,K](fp32) @ Yb^T, Yb = [b][4096][K] bf16.
// 128 x NTILE tile, 4 waves, 32x32x16 MFMA, BK=64, XOR-swizzled LDS.
// EPI 0: q/k f32 and v bf16 all written [bh][d][n] (coalesced over n).
// EPI 1: pwout f32 [b][m][4096].
template <int K, int EPI, int NTILE>
__global__ __launch_bounds__(256) void k_gemm_bf(
    const float* __restrict__ W, const u16* __restrict__ Yb,
    float* __restrict__ q_o, float* __restrict__ k_o,
    u16* __restrict__ v_t, int Mtiles) {
  constexpr int FN = NTILE >> 6;            // 2 for 128, 1 for 64
  constexpr int NT_CNT = NTOK / NTILE;
  __shared__ u16 Wl[128 * 64];
  __shared__ u16 Yl[NTILE * 64];
  int gid = blockIdx.x;
  int nt = gid % NT_CNT;
  int mt = (gid / NT_CNT) % Mtiles;
  int b = gid / (NT_CNT * Mtiles);
  int t = threadIdx.x;
  int w = t >> 6, l = t & 63;
  int wm = w >> 1, wn = w & 1;
  int hi = l >> 5, lq = l & 31;

  f32x16 acc[2][FN];
#pragma unroll
  for (int fm = 0; fm < 2; ++fm)
#pragma unroll
    for (int fn = 0; fn < FN; ++fn)
#pragma unroll
      for (int r = 0; r < 16; ++r) acc[fm][fn][r] = 0.f;

  const float* Wbase = W + (size_t)(mt * 128) * K;
  const u16* Ybase = Yb + ((size_t)(b * NTOK) + nt * NTILE) * K;

  for (int k0 = 0; k0 < K; k0 += 64) {
#pragma unroll
    for (int u = 0; u < 4; ++u) {           // W: 1024 granules of 8 bf16
      int gI = t + 256 * u;
      int row = gI >> 3, g = gI & 7;
      float4 f0 = *(const float4*)(Wbase + (size_t)row * K + k0 + g * 8);
      float4 f1 = *(const float4*)(Wbase + (size_t)row * K + k0 + g * 8 + 4);
      uint4 uu;
      uu.x = cvtpk(f0.x, f0.y); uu.y = cvtpk(f0.z, f0.w);
      uu.z = cvtpk(f1.x, f1.y); uu.w = cvtpk(f1.z, f1.w);
      *(uint4*)&Wl[row * 64 + 8 * (g ^ (row & 7))] = uu;
    }
#pragma unroll
    for (int u = 0; u < NTILE / 32; ++u) {  // Y: NTILE*8 granules
      int gI = t + 256 * u;
      int row = gI >> 3, g = gI & 7;
      uint4 yv = *(const uint4*)(Ybase + (size_t)row * K + k0 + g * 8);
      *(uint4*)&Yl[row * 64 + 8 * (g ^ (row & 7))] = yv;
    }
    __syncthreads();
#pragma unroll
    for (int ks = 0; ks < 4; ++ks) {
      bf16x8 aF[2], bF[FN];
#pragma unroll
      for (int fm = 0; fm < 2; ++fm) {
        int row = wm * 64 + fm * 32 + lq;
        aF[fm] = *(bf16x8*)&Wl[row * 64 + 8 * ((2 * ks + hi) ^ (row & 7))];
      }
#pragma unroll
      for (int fn = 0; fn < FN; ++fn) {
        int row = wn * 32 * FN + fn * 32 + lq;
        bF[fn] = *(bf16x8*)&Yl[row * 64 + 8 * ((2 * ks + hi) ^ (row & 7))];
      }
#pragma unroll
      for (int fm = 0; fm < 2; ++fm)
#pragma unroll
        for (int fn = 0; fn < FN; ++fn)
          acc[fm][fn] = __builtin_amdgcn_mfma_f32_32x32x16_bf16(
              aF[fm], bF[fn], acc[fm][fn], 0, 0, 0);
    }
    __syncthreads();
  }

#pragma unroll
  for (int fm = 0; fm < 2; ++fm)
#pragma unroll
    for (int fn = 0; fn < FN; ++fn)
#pragma unroll
      for (int reg = 0; reg < 16; ++reg) {
        int rl = (reg & 3) + 8 * (reg >> 2) + 4 * hi;
        int o = mt * 128 + wm * 64 + fm * 32 + rl;
        int n = nt * NTILE + wn * 32 * FN + fn * 32 + lq;
        float val = acc[fm][fn][reg];
        if (EPI == 0) {
          int part = o >> 8, rr = o & 255;
          int head = rr & 3, d = rr >> 2;
          size_t idx = ((size_t)(b * HEADS + head) * DH + d) * NTOK + n;
          if (part == 0) q_o[idx] = val;
          else if (part == 1) k_o[idx] = val;
          else v_t[idx] = (u16)f2bf1(val);
        } else {
          q_o[((size_t)(b * DIM) + o) * NTOK + n] = val;
        }
      }
}

// ---------------------------------------------------------------- kernel 3
// transposing per-head LN: reads q/k f32 [bh][d][n] coalesced, LN over d,
// writes bf16 [bh][n][64] (q scaled by QS). grid = bh(8) x nt(64) = 512.
__global__ __launch_bounds__(256) void k_lnqk_t(const float* __restrict__ qh,
    const float* __restrict__ kh, u16* __restrict__ qo, u16* __restrict__ ko,
    const float* __restrict__ nqw, const float* __restrict__ nqb,
    const float* __restrict__ nkw, const float* __restrict__ nkb) {
  __shared__ float ld[64][65];
  int bh = blockIdx.x >> 6, nt = blockIdx.x & 63;
  int head = bh & 3;
  int n0 = nt * 64;
  int t = threadIdx.x;
  int dg = t & 3, nn = t >> 2;          // compute map (dg fastest in lane)
  int dl = t >> 4, nc = t & 15;         // load map
#pragma unroll
  for (int m = 0; m < 2; ++m) {
    const float* src = (m ? kh : qh) + ((size_t)bh * DH) * NTOK + n0;
    const float* wp = (m ? nkw : nqw) + head * DH;
    const float* bp = (m ? nkb : nqb) + head * DH;
    u16* dst = (m ? ko : qo) + ((size_t)bh * NTOK + n0) * DH;
    if (m) __syncthreads();
#pragma unroll
    for (int pass = 0; pass < 4; ++pass) {
      int d = pass * 16 + dl;
      *(float4*)&ld[d][nc * 4] = *(const float4*)(src + (size_t)d * NTOK + nc * 4);
    }
    __syncthreads();
    float s1 = 0.f, s2 = 0.f;
#pragma unroll
    for (int i = 0; i < 16; ++i) {
      float v = ld[dg * 16 + i][nn];
      s1 += v; s2 += v * v;
    }
    s1 += __shfl_xor(s1, 1); s2 += __shfl_xor(s2, 1);
    s1 += __shfl_xor(s1, 2); s2 += __shfl_xor(s2, 2);
    float mu = s1 * (1.f / 64.f);
    float var = s2 * (1.f / 64.f) - mu * mu;
    float ri = rsqrtf(var + 1e-6f);
    float sc = m ? 1.f : QS;
    unsigned ow[8];
#pragma unroll
    for (int i = 0; i < 8; ++i) {
      int d0 = dg * 16 + 2 * i;
      float y0 = ((ld[d0][nn] - mu) * ri * wp[d0] + bp[d0]) * sc;
      float y1 = ((ld[d0 + 1][nn] - mu) * ri * wp[d0 + 1] + bp[d0 + 1]) * sc;
      ow[i] = packbf(y0, y1);
    }
    *(uint4*)(dst + (size_t)nn * DH + dg * 16) = *(uint4*)&ow[0];
    *(uint4*)(dst + (size_t)nn * DH + dg * 16 + 8) = *(uint4*)&ow[4];
  }
}

// ---------------------------------------------------------------- kernel 4
// MFMA flash attention (round-3 structure). Block = (bh, 128-q tile); 8
// waves = 4 qg x 2 kv-halves. Q bf16 [bh][n][64], K bf16 [bh][n][64],
// V^T bf16 [bh][d][n]. XOR-swizzled LDS, async-stage, exp2 softmax.
__global__ __launch_bounds__(512, 2) void k_attn2(
    const u16* __restrict__ qb, const u16* __restrict__ kb,
    const u16* __restrict__ vtb, const float* __restrict__ now,
    const float* __restrict__ nob, float* __restrict__ att) {
  __shared__ __align__(16) u16 kvbuf[16384];  // [half][K 4096 | V 4096]
  __shared__ float mlm[256], mll[256];
  __shared__ float nw[DH], nb[DH];
  const int bh = blockIdx.x >> 5, qt = blockIdx.x & 31;
  const int b = bh >> 2, head = bh & 3;
  const int t = threadIdx.x;
  const int w = t >> 6, l = t & 63;
  const int qg = w & 3, half = w >> 2;
  const int hi = l >> 5, lq = l & 31;
  if (t < DH) { nw[t] = now[head * DH + t]; nb[t] = nob[head * DH + t]; }

  const int q0 = qt * 128 + qg * 32;
  const u16* qrow = qb + (size_t)(bh * NTOK + q0 + lq) * DH;  // 64-u16 rows
  bf16x8 qf[4];
#pragma unroll
  for (int ks = 0; ks < 4; ++ks)
    qf[ks] = *(const bf16x8*)(qrow + 16 * ks + 8 * hi);

  // staging: threads [sh*256, sh*256+256) stage half sh
  const int st = t & 255, sh = t >> 8;
  const int r0s = st >> 3, g0s = st & 7;          // granule idx st
  const int r1s = (st + 256) >> 3, g1s = st & 7;  // granule idx st+256
  const u16* kbase = kb + (size_t)(bh * NTOK) * DH;
  const u16* vbase = vtb + (size_t)(bh * DH) * NTOK;
  uint4 kr0, kr1, vr0, vr1;

  auto loadTile = [&](int s) {
    int kvt = sh * 32 + s;
    kr0 = *(const uint4*)(kbase + (size_t)(kvt * 64 + r0s) * DH + g0s * 8);
    kr1 = *(const uint4*)(kbase + (size_t)(kvt * 64 + r1s) * DH + g1s * 8);
    vr0 = *(const uint4*)(vbase + (size_t)r0s * NTOK + kvt * 64 + g0s * 8);
    vr1 = *(const uint4*)(vbase + (size_t)r1s * NTOK + kvt * 64 + g1s * 8);
  };
  loadTile(0);

  f32x16 oT0, oT1;
#pragma unroll
  for (int i = 0; i < 16; ++i) { oT0[i] = 0.f; oT1[i] = 0.f; }
  float m_s = -1e30f, l_s = 0.f;
  int cur = 0; (void)cur;

  const u16* KL = kvbuf + half * 8192;
  const u16* VL = KL + 4096;

  for (int s = 0; s < 32; ++s) {
    __syncthreads();  // readers done with tile s-1
    *(uint4*)&kvbuf[sh * 8192 + r0s * 64 + 8 * (g0s ^ (r0s & 7))] = kr0;
    *(uint4*)&kvbuf[sh * 8192 + r1s * 64 + 8 * (g1s ^ (r1s & 7))] = kr1;
    *(uint4*)&kvbuf[sh * 8192 + 4096 + r0s * 64 + 8 * (g0s ^ (r0s & 7))] = vr0;
    *(uint4*)&kvbuf[sh * 8192 + 4096 + r1s * 64 + 8 * (g1s ^ (r1s & 7))] = vr1;
    __syncthreads();  // tile s visible
    if (s < 31) loadTile(s + 1);  // in flight under compute

    // ---- S^T = K . Q^T
    f32x16 sT0, sT1;
#pragma unroll
    for (int i = 0; i < 16; ++i) { sT0[i] = 0.f; sT1[i] = 0.f; }
#pragma unroll
    for (int ks = 0; ks < 4; ++ks) {
      bf16x8 a0 = *(bf16x8*)&KL[lq * 64 + 8 * ((2 * ks + hi) ^ (lq & 7))];
      bf16x8 a1 = *(bf16x8*)&KL[(32 + lq) * 64 + 8 * ((2 * ks + hi) ^ (lq & 7))];
      sT0 = __builtin_amdgcn_mfma_f32_32x32x16_bf16(a0, qf[ks], sT0, 0, 0, 0);
      sT1 = __builtin_amdgcn_mfma_f32_32x32x16_bf16(a1, qf[ks], sT1, 0, 0, 0);
    }
    // ---- online softmax (exp2 domain); lane owns q = q0+lq
    float mo = fmaxf(sT0[0], sT1[0]);
#pragma unroll
    for (int i = 1; i < 16; ++i) mo = fmaxf(mo, fmaxf(sT0[i], sT1[i]));
    mo = fmaxf(mo, __shfl_xor(mo, 32));
    float mn = fmaxf(m_s, mo);
    float alpha = exp2f(m_s - mn);
    m_s = mn;
    float p[32];
    float rs = 0.f;
#pragma unroll
    for (int i = 0; i < 16; ++i) {
      float p0 = exp2f(sT0[i] - mn);
      float p1 = exp2f(sT1[i] - mn);
      p[i] = p0; p[16 + i] = p1;
      rs += p0 + p1;
    }
    rs += __shfl_xor(rs, 32);
    l_s = l_s * alpha + rs;
#pragma unroll
    for (int i = 0; i < 16; ++i) { oT0[i] *= alpha; oT1[i] *= alpha; }
    // ---- P^T B-frags in-register
    bf16x8 pf[4];
#pragma unroll
    for (int ks = 0; ks < 4; ++ks) {
      int base = (ks >> 1) * 16 + 8 * (ks & 1);
      unsigned eL0 = cvtpk(p[base + 0], p[base + 1]);
      unsigned eL1 = cvtpk(p[base + 2], p[base + 3]);
      unsigned eH0 = cvtpk(p[base + 4], p[base + 5]);
      unsigned eH1 = cvtpk(p[base + 6], p[base + 7]);
      unsigned z0 = hi ? eL0 : eH0;
      unsigned z1 = hi ? eL1 : eH1;
      unsigned rr0 = (unsigned)__shfl_xor((int)z0, 32);
      unsigned rr1 = (unsigned)__shfl_xor((int)z1, 32);
      union { unsigned u[4]; bf16x8 v; } U;
      if (hi) { U.u[0] = rr0; U.u[1] = rr1; U.u[2] = eH0; U.u[3] = eH1; }
      else    { U.u[0] = eL0; U.u[1] = eL1; U.u[2] = rr0; U.u[3] = rr1; }
      pf[ks] = U.v;
    }
    // ---- O^T += V^T . P^T
#pragma unroll
    for (int ks = 0; ks < 4; ++ks) {
      bf16x8 v0 = *(bf16x8*)&VL[lq * 64 + 8 * ((2 * ks + hi) ^ (lq & 7))];
      bf16x8 v1 = *(bf16x8*)&VL[(32 + lq) * 64 + 8 * ((2 * ks + hi) ^ (lq & 7))];
      oT0 = __builtin_amdgcn_mfma_f32_32x32x16_bf16(v0, pf[ks], oT0, 0, 0, 0);
      oT1 = __builtin_amdgcn_mfma_f32_32x32x16_bf16(v1, pf[ks], oT1, 0, 0, 0);
    }
  }

  // ---- merge halves via LDS
  __syncthreads();
  float* mrg = (float*)kvbuf;
  if (half == 1) {
    float* mg = mrg + qg * 2048;
#pragma unroll
    for (int i = 0; i < 16; ++i) {
      mg[i * 64 + l] = oT0[i];
      mg[(16 + i) * 64 + l] = oT1[i];
    }
    mlm[qg * 64 + l] = m_s;
    mll[qg * 64 + l] = l_s;
  }
  __syncthreads();
  if (half == 0) {
    const float* mg = mrg + qg * 2048;
    float m1 = mlm[qg * 64 + l], l1 = mll[qg * 64 + l];
    float M = fmaxf(m_s, m1);
    float a0 = exp2f(m_s - M), a1 = exp2f(m1 - M);
    float L = l_s * a0 + l1 * a1;
    float inv = 1.f / L;
    float ov[32];
#pragma unroll
    for (int i = 0; i < 16; ++i) {
      ov[i] = (oT0[i] * a0 + mg[i * 64 + l] * a1) * inv;
      ov[16 + i] = (oT1[i] * a0 + mg[(16 + i) * 64 + l] * a1) * inv;
    }
    int n = q0 + lq;
    // skip: += v (bf16 V^T)
#pragma unroll
    for (int dt = 0; dt < 2; ++dt)
#pragma unroll
      for (int g = 0; g < 4; ++g)
#pragma unroll
        for (int r = 0; r < 4; ++r) {
          int d = dt * 32 + g * 8 + hi * 4 + r;
          ov[dt * 16 + g * 4 + r] +=
              bf2f(vtb[((size_t)(bh * DH) + d) * NTOK + n]);
        }
    float s1 = 0.f, s2 = 0.f;
#pragma unroll
    for (int i = 0; i < 32; ++i) { s1 += ov[i]; s2 += ov[i] * ov[i]; }
    s1 += __shfl_xor(s1, 32);
    s2 += __shfl_xor(s2, 32);
    float mu = s1 * (1.f / 64.f);
    float va = s2 * (1.f / 64.f) - mu * mu;
    float ri = rsqrtf(va + 1e-6f);
    float* ob = att + (size_t)b * INNER * NTOK + n;
#pragma unroll
    for (int dt = 0; dt < 2; ++dt)
#pragma unroll
      for (int g = 0; g < 4; ++g)
#pragma unroll
        for (int r = 0; r < 4; ++r) {
          int d = dt * 32 + g * 8 + hi * 4 + r;
          float y = (ov[dt * 16 + g * 4 + r] - mu) * ri * nw[d] + nb[d];
          ob[(size_t)(d * 4 + head) * NTOK] = y;
        }
  }
}

// ---------------------------------------------------------------- kernel 7
__global__ __launch_bounds__(256) void k_ln2d(const float* __restrict__ pw,
    const float* __restrict__ lnw, const float* __restrict__ lnb,
    float* __restrict__ out) {
  __shared__ float sh1[4][64], sh2[4][64];
  int b = blockIdx.x >> 6, nt = blockIdx.x & 63;
  int ln = threadIdx.x & 63, part = threadIdx.x >> 6;
  int n = nt * 64 + ln;
  const float* base = pw + (size_t)b * DIM * NTOK + n;
  float a1 = 0.f, a2 = 0.f;
  for (int c = part * 32; c < part * 32 + 32; ++c) {
    float v = base[(size_t)c * NTOK];
    a1 += v;
    a2 += v * v;
  }
  sh1[part][ln] = a1;
  sh2[part][ln] = a2;
  __syncthreads();
  float s1 = sh1[0][ln] + sh1[1][ln] + sh1[2][ln] + sh1[3][ln];
  float s2 = sh2[0][ln] + sh2[1][ln] + sh2[2][ln] + sh2[3][ln];
  float mu = s1 * (1.f / 128.f);
  float var = s2 * (1.f / 128.f) - mu * mu;
  float ri = rsqrtf(var + 1e-6f);
  float* ob = out + (size_t)b * DIM * NTOK + n;
  for (int c = part * 32; c < part * 32 + 32; ++c) {
    float v = base[(size_t)c * NTOK];
    ob[(size_t)c * NTOK] = (v - mu) * ri * lnw[c] + lnb[c];
  }
}

// ----------------------------------------------------------------
extern "C" void kernel_launch(void* const* d_in, const int* in_sizes, int n_in,
                              void* d_out, int out_size, void* d_ws,
                              size_t ws_size, hipStream_t stream) {
  const float* x      = (const float*)d_in[0];
  const float* pe_w   = (const float*)d_in[1];
  const float* pe_b   = (const float*)d_in[2];
  const float* qkv_dw = (const float*)d_in[3];
  const float* qkv_pw = (const float*)d_in[4];
  const float* out_dw = (const float*)d_in[5];
  const float* out_pw = (const float*)d_in[6];
  const float* nq_w   = (const float*)d_in[7];
  const float* nq_b   = (const float*)d_in[8];
  const float* nk_w   = (const float*)d_in[9];
  const float* nk_b   = (const float*)d_in[10];
  const float* no_w   = (const float*)d_in[11];
  const float* no_b   = (const float*)d_in[12];
  const float* ln_w   = (const float*)d_in[13];
  const float* ln_b   = (const float*)d_in[14];

  float* ws = (float*)d_ws;
  // layout (float offsets), peak 7.86M floats = 31.5MB (same as round 3):
  u16*   dwyb = (u16*)ws;                               // [2][4096][128] bf16
  float* qhb  = ws + (1u << 19);                        // [8][64][4096] f32
  float* khb  = ws + (1u << 19) + (1u << 21);           // [8][64][4096] f32
  u16*   vtb  = (u16*)(ws + (1u << 19) + (2u << 21));   // [8][64][4096] bf16
  u16*   qbb  = (u16*)(ws + (1u << 19) + (2u << 21) + (1u << 20));  // [8][4096][64] bf16
  u16*   kbb  = (u16*)(ws + (1u << 19) + (2u << 21) + (2u << 20));  // [8][4096][64] bf16
  float* att  = qhb;                                    // reuse (q f32 dead)
  u16*   db16 = (u16*)khb;                              // reuse (k f32 dead)
  float* pwout = qhb;                                   // reuse (att dead after k_dw)
  float* outp = (float*)d_out;

  k_pe_dw<<<dim3(128), dim3(256), 0, stream>>>(x, pe_w, pe_b, qkv_dw, dwyb);
  k_gemm_bf<128, 0, 128><<<dim3(BB * 6 * 32), dim3(256), 0, stream>>>(
      qkv_pw, dwyb, qhb, khb, vtb, 6);
  k_lnqk_t<<<dim3(512), dim3(256), 0, stream>>>(
      qhb, khb, qbb, kbb, nq_w, nq_b, nk_w, nk_b);
  k_attn2<<<dim3(256), dim3(512), 0, stream>>>(qbb, kbb, vtb, no_w, no_b, att);
  k_dw<<<dim3(256), dim3(256), 0, stream>>>(att, out_dw, db16);
  k_gemm_bf<256, 1, 64><<<dim3(BB * 64), dim3(256), 0, stream>>>(
      out_pw, db16, pwout, nullptr, nullptr, 1);
  k_ln2d<<<dim3(BB * 64), dim3(256), 0, stream>>>(pwout, ln_w, ln_b, outp);
}

// Round 6
// 223.319 us; speedup vs baseline: 1.7522x; 1.3277x over previous
//
#include <hip/hip_runtime.h>

#define BB 2
#define NTOK 4096
#define DIM 128
#define INNER 256
#define HEADS 4
#define DH 64
#define QS 0.18033688011112043f  // 0.125 * log2(e)

typedef unsigned short u16;
typedef __attribute__((ext_vector_type(8))) short bf16x8;
typedef __attribute__((ext_vector_type(16))) float f32x16;

__device__ inline unsigned f2bf1(float f) {
  union { float f; unsigned u; } a; a.f = f;
  return (a.u + 0x7fffu + ((a.u >> 16) & 1u)) >> 16;  // RNE
}
__device__ inline unsigned packbf(float lo, float hi) {
  return f2bf1(lo) | (f2bf1(hi) << 16);
}
__device__ inline float bf2f(u16 h) {
  union { unsigned u; float f; } a; a.u = ((unsigned)h) << 16;
  return a.f;
}
__device__ inline unsigned cvtpk(float lo, float hi) {
  unsigned r;
  asm("v_cvt_pk_bf16_f32 %0, %1, %2" : "=v"(r) : "v"(lo), "v"(hi));
  return r;
}

// ---------------------------------------------------------------- conv
// depthwise 3x3 (SAME) with optional pos-enc, LDS-tiled.
// block: 16 channels x 512-px strip (8 image rows + halo). out bf16 [b][n][C].
template <int C, bool PE>
__global__ __launch_bounds__(256) void k_dwconv(const float* __restrict__ x,
    const float* __restrict__ pew, const float* __restrict__ peb,
    const float* __restrict__ dw, u16* __restrict__ out) {
  constexpr int CG = C / 16;
  __shared__ float ld[16][640];  // 10 rows x 64
  int bid = blockIdx.x;
  int strip = bid & 7;
  int cg = (bid >> 3) % CG;
  int b = bid / (8 * CG);
  int r0 = strip * 8;
  int t = threadIdx.x;
#pragma unroll
  for (int c = 0; c < 16; ++c) {
    int gc = cg * 16 + c;
    const float* xb = x + ((size_t)(b * C + gc)) * NTOK;
    float s0 = 0.f, s1 = 0.f, pb = 0.f;
    if (PE) {
      s0 = pew[gc * 2] * (1.f / 63.f);
      s1 = pew[gc * 2 + 1] * (1.f / 63.f);
      pb = peb[gc];
    }
#pragma unroll
    for (int u = 0; u < 3; ++u) {
      int pos = t + 256 * u;
      if (pos < 640) {
        int rr = r0 - 1 + (pos >> 6);
        int col = pos & 63;
        float v = 0.f;
        if ((unsigned)rr < 64u) {
          v = xb[rr * 64 + col];
          if (PE) v += rr * s0 + col * s1 + pb;
        }
        ld[c][pos] = v;
      }
    }
  }
  __syncthreads();
  float accv[2][16];
#pragma unroll
  for (int c = 0; c < 16; ++c) {
    const float* wp = dw + (cg * 16 + c) * 9;
    float w0 = wp[0], w1 = wp[1], w2 = wp[2], w3 = wp[3], w4 = wp[4];
    float w5 = wp[5], w6 = wp[6], w7 = wp[7], w8 = wp[8];
#pragma unroll
    for (int pp = 0; pp < 2; ++pp) {
      int p = t + 256 * pp;
      int lr = (p >> 6) + 1;
      int j = p & 63;
      const float* rm = &ld[c][(lr - 1) * 64];
      const float* rc = &ld[c][lr * 64];
      const float* rp = &ld[c][(lr + 1) * 64];
      float acc = rm[j] * w1 + rc[j] * w4 + rp[j] * w7;
      if (j > 0)  acc += rm[j - 1] * w0 + rc[j - 1] * w3 + rp[j - 1] * w6;
      if (j < 63) acc += rm[j + 1] * w2 + rc[j + 1] * w5 + rp[j + 1] * w8;
      accv[pp][c] = acc;
    }
  }
#pragma unroll
  for (int pp = 0; pp < 2; ++pp) {
    int p = t + 256 * pp;
    unsigned ow[8];
#pragma unroll
    for (int q = 0; q < 8; ++q) ow[q] = packbf(accv[pp][2 * q], accv[pp][2 * q + 1]);
    u16* ob = out + ((size_t)(b * NTOK) + strip * 512 + p) * C + cg * 16;
    *(uint4*)(ob) = *(uint4*)&ow[0];
    *(uint4*)(ob + 8) = *(uint4*)&ow[4];
  }
}

// ---------------------------------------------------------------- kernel 2
// qkv MFMA GEMM: C[768,4096] = W(fp32) @ Yb^T, Yb=[b][4096][128] bf16.
// 128x128 tile, 4 waves, 32x32x16, BK=64, XOR-swizzled LDS.
// Epilogue: q/k f32 and v bf16 written [bh][d][n] (coalesced over n).
__global__ __launch_bounds__(256) void k_gemm_qkv(
    const float* __restrict__ W, const u16* __restrict__ Yb,
    float* __restrict__ q_o, float* __restrict__ k_o, u16* __restrict__ v_t) {
  __shared__ u16 Wl[128 * 64];
  __shared__ u16 Yl[128 * 64];
  int gid = blockIdx.x;
  int nt = gid & 31;
  int mt = (gid >> 5) % 6;
  int b = gid / 192;
  int t = threadIdx.x;
  int w = t >> 6, l = t & 63;
  int wm = w >> 1, wn = w & 1;
  int hi = l >> 5, lq = l & 31;

  f32x16 acc[2][2];
#pragma unroll
  for (int fm = 0; fm < 2; ++fm)
#pragma unroll
    for (int fn = 0; fn < 2; ++fn)
#pragma unroll
      for (int r = 0; r < 16; ++r) acc[fm][fn][r] = 0.f;

  const float* Wbase = W + (size_t)(mt * 128) * 128;
  const u16* Ybase = Yb + ((size_t)(b * NTOK) + nt * 128) * 128;

  for (int k0 = 0; k0 < 128; k0 += 64) {
#pragma unroll
    for (int u = 0; u < 4; ++u) {
      int gI = t + 256 * u;
      int row = gI >> 3, g = gI & 7;
      float4 f0 = *(const float4*)(Wbase + (size_t)row * 128 + k0 + g * 8);
      float4 f1 = *(const float4*)(Wbase + (size_t)row * 128 + k0 + g * 8 + 4);
      uint4 uu;
      uu.x = cvtpk(f0.x, f0.y); uu.y = cvtpk(f0.z, f0.w);
      uu.z = cvtpk(f1.x, f1.y); uu.w = cvtpk(f1.z, f1.w);
      *(uint4*)&Wl[row * 64 + 8 * (g ^ (row & 7))] = uu;
      uint4 yv = *(const uint4*)(Ybase + (size_t)row * 128 + k0 + g * 8);
      *(uint4*)&Yl[row * 64 + 8 * (g ^ (row & 7))] = yv;
    }
    __syncthreads();
#pragma unroll
    for (int ks = 0; ks < 4; ++ks) {
      bf16x8 aF[2], bF[2];
#pragma unroll
      for (int fm = 0; fm < 2; ++fm) {
        int row = wm * 64 + fm * 32 + lq;
        aF[fm] = *(bf16x8*)&Wl[row * 64 + 8 * ((2 * ks + hi) ^ (row & 7))];
      }
#pragma unroll
      for (int fn = 0; fn < 2; ++fn) {
        int row = wn * 64 + fn * 32 + lq;
        bF[fn] = *(bf16x8*)&Yl[row * 64 + 8 * ((2 * ks + hi) ^ (row & 7))];
      }
#pragma unroll
      for (int fm = 0; fm < 2; ++fm)
#pragma unroll
        for (int fn = 0; fn < 2; ++fn)
          acc[fm][fn] = __builtin_amdgcn_mfma_f32_32x32x16_bf16(
              aF[fm], bF[fn], acc[fm][fn], 0, 0, 0);
    }
    __syncthreads();
  }

#pragma unroll
  for (int fm = 0; fm < 2; ++fm)
#pragma unroll
    for (int fn = 0; fn < 2; ++fn)
#pragma unroll
      for (int reg = 0; reg < 16; ++reg) {
        int rl = (reg & 3) + 8 * (reg >> 2) + 4 * hi;
        int o = mt * 128 + wm * 64 + fm * 32 + rl;
        int n = nt * 128 + wn * 64 + fn * 32 + lq;
        float val = acc[fm][fn][reg];
        int part = o >> 8, rr = o & 255;
        int head = rr & 3, d = rr >> 2;
        size_t idx = ((size_t)(b * HEADS + head) * DH + d) * NTOK + n;
        if (part == 0) q_o[idx] = val;
        else if (part == 1) k_o[idx] = val;
        else v_t[idx] = (u16)f2bf1(val);
      }
}

// ---------------------------------------------------------------- kernel 3
// transposing per-head LN: reads q/k f32 [bh][d][n] coalesced, LN over d,
// writes bf16 [bh][n][64] (q scaled by QS). grid = bh(8) x nt(64) = 512.
__global__ __launch_bounds__(256) void k_lnqk_t(const float* __restrict__ qh,
    const float* __restrict__ kh, u16* __restrict__ qo, u16* __restrict__ ko,
    const float* __restrict__ nqw, const float* __restrict__ nqb,
    const float* __restrict__ nkw, const float* __restrict__ nkb) {
  __shared__ float ld[64][65];
  int bh = blockIdx.x >> 6, nt = blockIdx.x & 63;
  int head = bh & 3;
  int n0 = nt * 64;
  int t = threadIdx.x;
  int dg = t & 3, nn = t >> 2;
  int dl = t >> 4, nc = t & 15;
#pragma unroll
  for (int m = 0; m < 2; ++m) {
    const float* src = (m ? kh : qh) + ((size_t)bh * DH) * NTOK + n0;
    const float* wp = (m ? nkw : nqw) + head * DH;
    const float* bp = (m ? nkb : nqb) + head * DH;
    u16* dst = (m ? ko : qo) + ((size_t)bh * NTOK + n0) * DH;
    if (m) __syncthreads();
#pragma unroll
    for (int pass = 0; pass < 4; ++pass) {
      int d = pass * 16 + dl;
      *(float4*)&ld[d][nc * 4] = *(const float4*)(src + (size_t)d * NTOK + nc * 4);
    }
    __syncthreads();
    float s1 = 0.f, s2 = 0.f;
#pragma unroll
    for (int i = 0; i < 16; ++i) {
      float v = ld[dg * 16 + i][nn];
      s1 += v; s2 += v * v;
    }
    s1 += __shfl_xor(s1, 1); s2 += __shfl_xor(s2, 1);
    s1 += __shfl_xor(s1, 2); s2 += __shfl_xor(s2, 2);
    float mu = s1 * (1.f / 64.f);
    float var = s2 * (1.f / 64.f) - mu * mu;
    float ri = rsqrtf(var + 1e-6f);
    float sc = m ? 1.f : QS;
    unsigned ow[8];
#pragma unroll
    for (int i = 0; i < 8; ++i) {
      int d0 = dg * 16 + 2 * i;
      float y0 = ((ld[d0][nn] - mu) * ri * wp[d0] + bp[d0]) * sc;
      float y1 = ((ld[d0 + 1][nn] - mu) * ri * wp[d0 + 1] + bp[d0 + 1]) * sc;
      ow[i] = packbf(y0, y1);
    }
    *(uint4*)(dst + (size_t)nn * DH + dg * 16) = *(uint4*)&ow[0];
    *(uint4*)(dst + (size_t)nn * DH + dg * 16 + 8) = *(uint4*)&ow[4];
  }
}

// ---------------------------------------------------------------- kernel 4
// MFMA flash attention. Block = (bh, 64-q tile); 8 waves = 2 qg x 4 kv-
// quarters (1024 kv each, 32 tiles of 32). KVBLK=32; K [32kv][64d], V^T
// [64d][32kv] bf16 LDS, XOR swizzle; T13 defer-max; T14 async-stage;
// 2-round pairwise merge. Epilogue: O/l + v skip, head-LN, scatter.
__global__ __launch_bounds__(512, 4) void k_attn4(
    const u16* __restrict__ qb, const u16* __restrict__ kb,
    const u16* __restrict__ vtb, const float* __restrict__ now,
    const float* __restrict__ nob, float* __restrict__ att) {
  __shared__ __align__(16) u16 kvbuf[16384];  // 32KB: 4 quarters x (K 4KB|V 4KB)
  __shared__ float mlm[256], mll[256];
  __shared__ float nw[DH], nb[DH];
  const int bh = blockIdx.x >> 6, qt = blockIdx.x & 63;
  const int b = bh >> 2, head = bh & 3;
  const int t = threadIdx.x;
  const int w = t >> 6, l = t & 63;
  const int qg = w & 1, h = w >> 1;   // 2 q-groups x 4 kv-quarters
  const int hi = l >> 5, lq = l & 31;
  if (t < DH) { nw[t] = now[head * DH + t]; nb[t] = nob[head * DH + t]; }

  const int q0 = qt * 64 + qg * 32;
  const u16* qrow = qb + (size_t)(bh * NTOK + q0 + lq) * DH;
  bf16x8 qf[4];
#pragma unroll
  for (int ks = 0; ks < 4; ++ks)
    qf[ks] = *(const bf16x8*)(qrow + 16 * ks + 8 * hi);

  // staging: 128 threads per quarter (the quarter's own 2 waves)
  const int st = t & 127;
  const int KQs = h * 4096, VQs = h * 4096 + 2048;
  const u16* kbase = kb + (size_t)(bh * NTOK) * DH;
  const u16* vbase = vtb + (size_t)(bh * DH) * NTOK;
  uint4 kr0, kr1, vr0, vr1;
  const int krow = st >> 3, kg = st & 7;
  const int vrow = st >> 2, vg = st & 3;

  auto loadTile = [&](int s) {
    int kv0 = h * 1024 + s * 32;
    kr0 = *(const uint4*)(kbase + (size_t)(kv0 + krow) * DH + kg * 8);
    kr1 = *(const uint4*)(kbase + (size_t)(kv0 + krow + 16) * DH + kg * 8);
    vr0 = *(const uint4*)(vbase + (size_t)vrow * NTOK + kv0 + vg * 8);
    vr1 = *(const uint4*)(vbase + (size_t)(vrow + 32) * NTOK + kv0 + vg * 8);
  };
  loadTile(0);

  f32x16 oT0, oT1;
#pragma unroll
  for (int i = 0; i < 16; ++i) { oT0[i] = 0.f; oT1[i] = 0.f; }
  float m_s = -1e30f, l_s = 0.f;
  const u16* KL = kvbuf + KQs;
  const u16* VL = kvbuf + VQs;

  for (int s = 0; s < 32; ++s) {
    __syncthreads();  // readers done with tile s-1
    *(uint4*)&kvbuf[KQs + krow * 64 + 8 * (kg ^ (krow & 7))] = kr0;
    *(uint4*)&kvbuf[KQs + (krow + 16) * 64 + 8 * (kg ^ ((krow + 16) & 7))] = kr1;
    *(uint4*)&kvbuf[VQs + vrow * 32 + 8 * (vg ^ ((vrow >> 1) & 3))] = vr0;
    *(uint4*)&kvbuf[VQs + (vrow + 32) * 32 + 8 * (vg ^ (((vrow + 32) >> 1) & 3))] = vr1;
    __syncthreads();  // tile s visible
    if (s < 31) loadTile(s + 1);

    // ---- S^T = K . Q^T  (one 32x32 tile, k = d = 64)
    f32x16 sT;
#pragma unroll
    for (int i = 0; i < 16; ++i) sT[i] = 0.f;
#pragma unroll
    for (int ks = 0; ks < 4; ++ks) {
      bf16x8 a = *(bf16x8*)&KL[lq * 64 + 8 * ((2 * ks + hi) ^ (lq & 7))];
      sT = __builtin_amdgcn_mfma_f32_32x32x16_bf16(a, qf[ks], sT, 0, 0, 0);
    }
    // ---- online softmax (exp2 domain) + defer-max
    float mo = sT[0];
#pragma unroll
    for (int i = 1; i < 16; ++i) mo = fmaxf(mo, sT[i]);
    mo = fmaxf(mo, __shfl_xor(mo, 32));
    float mn = fmaxf(m_s, mo);
    if (!__all(mn - m_s <= 8.0f)) {
      float alpha = exp2f(m_s - mn);
      m_s = mn;
      l_s *= alpha;
#pragma unroll
      for (int i = 0; i < 16; ++i) { oT0[i] *= alpha; oT1[i] *= alpha; }
    }
    unsigned pw[8];
    float rs = 0.f;
#pragma unroll
    for (int j = 0; j < 8; ++j) {
      float e0 = exp2f(sT[2 * j] - m_s);
      float e1 = exp2f(sT[2 * j + 1] - m_s);
      rs += e0 + e1;
      pw[j] = cvtpk(e0, e1);
    }
    rs += __shfl_xor(rs, 32);
    l_s += rs;
    // ---- P^T B-frags in-register (2 k-slices of 16)
    bf16x8 pf[2];
#pragma unroll
    for (int ks = 0; ks < 2; ++ks) {
      unsigned z0 = hi ? pw[4 * ks] : pw[4 * ks + 2];
      unsigned z1 = hi ? pw[4 * ks + 1] : pw[4 * ks + 3];
      unsigned r0 = (unsigned)__shfl_xor((int)z0, 32);
      unsigned r1 = (unsigned)__shfl_xor((int)z1, 32);
      union { unsigned u[4]; bf16x8 v; } U;
      if (hi) { U.u[0] = r0; U.u[1] = r1; U.u[2] = pw[4 * ks + 2]; U.u[3] = pw[4 * ks + 3]; }
      else    { U.u[0] = pw[4 * ks]; U.u[1] = pw[4 * ks + 1]; U.u[2] = r0; U.u[3] = r1; }
      pf[ks] = U.v;
    }
    // ---- O^T += V^T . P^T
#pragma unroll
    for (int ks = 0; ks < 2; ++ks) {
      bf16x8 v0 = *(bf16x8*)&VL[lq * 32 + 8 * ((2 * ks + hi) ^ ((lq >> 1) & 3))];
      bf16x8 v1 = *(bf16x8*)&VL[(32 + lq) * 32 + 8 * ((2 * ks + hi) ^ (((32 + lq) >> 1) & 3))];
      oT0 = __builtin_amdgcn_mfma_f32_32x32x16_bf16(v0, pf[ks], oT0, 0, 0, 0);
      oT1 = __builtin_amdgcn_mfma_f32_32x32x16_bf16(v1, pf[ks], oT1, 0, 0, 0);
    }
  }

  // ---- 2-round pairwise merge of the 4 kv-quarters (reuse kvbuf as f32)
  float* mrg = (float*)kvbuf;  // 4 slots x 2048 f32
  __syncthreads();
  if (h >= 2) {  // round A writers: h=2 -> slots 0/1, h=3 -> slots 2/3
    float* mg = mrg + ((h - 2) * 2 + qg) * 2048;
#pragma unroll
    for (int i = 0; i < 16; ++i) {
      mg[i * 64 + l] = oT0[i];
      mg[(16 + i) * 64 + l] = oT1[i];
    }
    mlm[((h - 2) * 2 + qg) * 64 + l] = m_s;
    mll[((h - 2) * 2 + qg) * 64 + l] = l_s;
  }
  __syncthreads();
  if (h < 2) {   // round A mergers: h=0 merges slot qg, h=1 merges slot 2+qg
    int slot = h * 2 + qg;
    const float* mg = mrg + slot * 2048;
    float m1 = mlm[slot * 64 + l], l1 = mll[slot * 64 + l];
    float M = fmaxf(m_s, m1);
    float a0 = exp2f(m_s - M), a1 = exp2f(m1 - M);
#pragma unroll
    for (int i = 0; i < 16; ++i) {
      oT0[i] = oT0[i] * a0 + mg[i * 64 + l] * a1;
      oT1[i] = oT1[i] * a0 + mg[(16 + i) * 64 + l] * a1;
    }
    l_s = l_s * a0 + l1 * a1;
    m_s = M;
  }
  __syncthreads();
  if (h == 1) {  // round B writer
    float* mg = mrg + qg * 2048;
#pragma unroll
    for (int i = 0; i < 16; ++i) {
      mg[i * 64 + l] = oT0[i];
      mg[(16 + i) * 64 + l] = oT1[i];
    }
    mlm[qg * 64 + l] = m_s;
    mll[qg * 64 + l] = l_s;
  }
  __syncthreads();
  if (h == 0) {  // final merge + epilogue
    const float* mg = mrg + qg * 2048;
    float m1 = mlm[qg * 64 + l], l1 = mll[qg * 64 + l];
    float M = fmaxf(m_s, m1);
    float a0 = exp2f(m_s - M), a1 = exp2f(m1 - M);
    float L = l_s * a0 + l1 * a1;
    float inv = 1.f / L;
    float ov[32];
#pragma unroll
    for (int i = 0; i < 16; ++i) {
      ov[i] = (oT0[i] * a0 + mg[i * 64 + l] * a1) * inv;
      ov[16 + i] = (oT1[i] * a0 + mg[(16 + i) * 64 + l] * a1) * inv;
    }
    int n = q0 + lq;
#pragma unroll
    for (int dt = 0; dt < 2; ++dt)
#pragma unroll
      for (int g = 0; g < 4; ++g)
#pragma unroll
        for (int r = 0; r < 4; ++r) {
          int d = dt * 32 + g * 8 + hi * 4 + r;
          ov[dt * 16 + g * 4 + r] +=
              bf2f(vtb[((size_t)(bh * DH) + d) * NTOK + n]);
        }
    float s1 = 0.f, s2 = 0.f;
#pragma unroll
    for (int i = 0; i < 32; ++i) { s1 += ov[i]; s2 += ov[i] * ov[i]; }
    s1 += __shfl_xor(s1, 32);
    s2 += __shfl_xor(s2, 32);
    float mu = s1 * (1.f / 64.f);
    float va = s2 * (1.f / 64.f) - mu * mu;
    float ri = rsqrtf(va + 1e-6f);
    float* ob = att + (size_t)b * INNER * NTOK + n;
#pragma unroll
    for (int dt = 0; dt < 2; ++dt)
#pragma unroll
      for (int g = 0; g < 4; ++g)
#pragma unroll
        for (int r = 0; r < 4; ++r) {
          int d = dt * 32 + g * 8 + hi * 4 + r;
          float y = (ov[dt * 16 + g * 4 + r] - mu) * ri * nw[d] + nb[d];
          ob[(size_t)(d * 4 + head) * NTOK] = y;
        }
  }
}

// ---------------------------------------------------------------- kernel 6
// out MFMA GEMM fused with LayerNorm2d. C[128,4096] = out_pw @ db^T,
// db = [b][4096][256] bf16. M=128 (one tile), NTILE=64, 4 waves.
// LN over the 128 output channels per column, write d_out f32 [b][c][n].
__global__ __launch_bounds__(256) void k_gemm_ln(
    const float* __restrict__ W, const u16* __restrict__ Yb,
    const float* __restrict__ lnw, const float* __restrict__ lnb,
    float* __restrict__ out) {
  __shared__ u16 Wl[128 * 64];
  __shared__ u16 Yl[64 * 64];
  __shared__ float red[256];
  int gid = blockIdx.x;
  int nt = gid & 63;
  int b = gid >> 6;
  int t = threadIdx.x;
  int w = t >> 6, l = t & 63;
  int wm = w >> 1, wn = w & 1;
  int hi = l >> 5, lq = l & 31;

  f32x16 acc[2];
#pragma unroll
  for (int fm = 0; fm < 2; ++fm)
#pragma unroll
    for (int r = 0; r < 16; ++r) acc[fm][r] = 0.f;

  const u16* Ybase = Yb + ((size_t)(b * NTOK) + nt * 64) * INNER;

  for (int k0 = 0; k0 < 256; k0 += 64) {
#pragma unroll
    for (int u = 0; u < 4; ++u) {
      int gI = t + 256 * u;
      int row = gI >> 3, g = gI & 7;
      float4 f0 = *(const float4*)(W + (size_t)row * 256 + k0 + g * 8);
      float4 f1 = *(const float4*)(W + (size_t)row * 256 + k0 + g * 8 + 4);
      uint4 uu;
      uu.x = cvtpk(f0.x, f0.y); uu.y = cvtpk(f0.z, f0.w);
      uu.z = cvtpk(f1.x, f1.y); uu.w = cvtpk(f1.z, f1.w);
      *(uint4*)&Wl[row * 64 + 8 * (g ^ (row & 7))] = uu;
    }
#pragma unroll
    for (int u = 0; u < 2; ++u) {
      int gI = t + 256 * u;
      int row = gI >> 3, g = gI & 7;
      uint4 yv = *(const uint4*)(Ybase + (size_t)row * 256 + k0 + g * 8);
      *(uint4*)&Yl[row * 64 + 8 * (g ^ (row & 7))] = yv;
    }
    __syncthreads();
#pragma unroll
    for (int ks = 0; ks < 4; ++ks) {
      bf16x8 aF[2], bF;
#pragma unroll
      for (int fm = 0; fm < 2; ++fm) {
        int row = wm * 64 + fm * 32 + lq;
        aF[fm] = *(bf16x8*)&Wl[row * 64 + 8 * ((2 * ks + hi) ^ (row & 7))];
      }
      {
        int row = wn * 32 + lq;
        bF = *(bf16x8*)&Yl[row * 64 + 8 * ((2 * ks + hi) ^ (row & 7))];
      }
#pragma unroll
      for (int fm = 0; fm < 2; ++fm)
        acc[fm] = __builtin_amdgcn_mfma_f32_32x32x16_bf16(aF[fm], bF, acc[fm], 0, 0, 0);
    }
    __syncthreads();
  }

  // ---- LN over 128 channels at each column
  float s1 = 0.f, s2 = 0.f;
#pragma unroll
  for (int fm = 0; fm < 2; ++fm)
#pragma unroll
    for (int r = 0; r < 16; ++r) {
      float v = acc[fm][r];
      s1 += v; s2 += v * v;
    }
  s1 += __shfl_xor(s1, 32);
  s2 += __shfl_xor(s2, 32);
  int col = wn * 32 + lq;
  if (hi == 0) { red[wm * 128 + col] = s1; red[wm * 128 + 64 + col] = s2; }
  __syncthreads();
  float t1 = red[col] + red[128 + col];
  float t2 = red[64 + col] + red[192 + col];
  float mu = t1 * (1.f / 128.f);
  float var = t2 * (1.f / 128.f) - mu * mu;
  float ri = rsqrtf(var + 1e-6f);
  int n = nt * 64 + col;
  float* ob = out + (size_t)b * DIM * NTOK + n;
#pragma unroll
  for (int fm = 0; fm < 2; ++fm)
#pragma unroll
    for (int r = 0; r < 16; ++r) {
      int m = wm * 64 + fm * 32 + (r & 3) + 8 * (r >> 2) + 4 * hi;
      float y = (acc[fm][r] - mu) * ri * lnw[m] + lnb[m];
      ob[(size_t)m * NTOK] = y;
    }
}

// ----------------------------------------------------------------
extern "C" void kernel_launch(void* const* d_in, const int* in_sizes, int n_in,
                              void* d_out, int out_size, void* d_ws,
                              size_t ws_size, hipStream_t stream) {
  const float* x      = (const float*)d_in[0];
  const float* pe_w   = (const float*)d_in[1];
  const float* pe_b   = (const float*)d_in[2];
  const float* qkv_dw = (const float*)d_in[3];
  const float* qkv_pw = (const float*)d_in[4];
  const float* out_dw = (const float*)d_in[5];
  const float* out_pw = (const float*)d_in[6];
  const float* nq_w   = (const float*)d_in[7];
  const float* nq_b   = (const float*)d_in[8];
  const float* nk_w   = (const float*)d_in[9];
  const float* nk_b   = (const float*)d_in[10];
  const float* no_w   = (const float*)d_in[11];
  const float* no_b   = (const float*)d_in[12];
  const float* ln_w   = (const float*)d_in[13];
  const float* ln_b   = (const float*)d_in[14];

  float* ws = (float*)d_ws;
  u16*   dwyb = (u16*)ws;                               // [2][4096][128] bf16
  float* qhb  = ws + (1u << 19);                        // [8][64][4096] f32
  float* khb  = ws + (1u << 19) + (1u << 21);           // [8][64][4096] f32
  u16*   vtb  = (u16*)(ws + (1u << 19) + (2u << 21));   // [8][64][4096] bf16
  u16*   qbb  = (u16*)(ws + (1u << 19) + (2u << 21) + (1u << 20));  // [8][4096][64]
  u16*   kbb  = (u16*)(ws + (1u << 19) + (2u << 21) + (2u << 20));  // [8][4096][64]
  float* att  = qhb;                                    // reuse (q f32 dead)
  u16*   db16 = (u16*)khb;                              // reuse (k f32 dead)
  float* outp = (float*)d_out;

  k_dwconv<DIM, true><<<dim3(128), dim3(256), 0, stream>>>(
      x, pe_w, pe_b, qkv_dw, dwyb);
  k_gemm_qkv<<<dim3(BB * 6 * 32), dim3(256), 0, stream>>>(
      qkv_pw, dwyb, qhb, khb, vtb);
  k_lnqk_t<<<dim3(512), dim3(256), 0, stream>>>(
      qhb, khb, qbb, kbb, nq_w, nq_b, nk_w, nk_b);
  k_attn4<<<dim3(512), dim3(512), 0, stream>>>(qbb, kbb, vtb, no_w, no_b, att);
  k_dwconv<INNER, false><<<dim3(256), dim3(256), 0, stream>>>(
      att, nullptr, nullptr, out_dw, db16);
  k_gemm_ln<<<dim3(BB * 64), dim3(256), 0, stream>>>(
      out_pw, db16, ln_w, ln_b, outp);
}